// Round 1
// baseline (119.956 us; speedup 1.0000x reference)
//
#include <hip/hip_runtime.h>
#include <math.h>

// ParametricDrumSynth on MI355X.
// Structure: one workgroup, 1024 threads.
//   Pass 1: blocked affine scan for the one-pole lowpass (c=0.1).
//   Pass 2: rebuild filtered signal + synthesize transient -> stash in d_out.
//   Pass 3: resonator recurrence.
//       Fast path (delay integral, the benchmark case: 48000/150 = 320.0):
//         out[i] = tr[i] + fb*out[i-B]  -> B independent register-carried
//         chains (residue classes mod B), final output fused into the walk.
//       General path: banded two-phase update (band = floor(delay)), with
//         frontier guards reproducing the reference scan's
//         "not-yet-written reads as 0" semantics.
constexpr int kN = 24000;   // num_samples
constexpr int kT = 1024;    // threads (16 waves)

__global__ __launch_bounds__(kT) void drum_synth_kernel(
    const float* __restrict__ params,
    const float* __restrict__ noise_t,
    const float* __restrict__ noise_n,
    float* __restrict__ out)
{
  __shared__ float sA[kT];
  __shared__ float sB[kT];

  const int tid = threadIdx.x;

  const float decay_t = params[1];
  const float freq_t  = params[2];
  const float sat     = params[3];
  const float gain_t  = params[4];
  const float freq_r  = params[5];
  const float fb      = params[6];
  const float gain_r  = params[7];
  const float att_n   = params[8];
  const float dec_n   = params[9];
  const float gain_n  = params[10];

  const float c   = 0.1f;          // NOISE_CUTOFF
  const float a   = 0.9f;          // 1 - cutoff
  const float inv = 1.0f / (float)(kN - 1);
  const float w   = 6.283185307179586f * freq_t;
  const float d20 = decay_t * 20.0f;
  const float gh  = gain_t * 0.5f;

  const int L = (kN + kT - 1) / kT;      // 24
  const int s = tid * L;
  const int e = (s + L < kN) ? (s + L) : kN;

  // ---------- Pass 1: per-chunk affine composition (y_out = A*y_in + B) ----
  float A = 1.0f, Bv = 0.0f;
  for (int i = s; i < e; ++i) {
    float x = noise_t[i];
    Bv = c * x + a * Bv;
    A *= a;
  }
  sA[tid] = A; sB[tid] = Bv;
  __syncthreads();

  // Hillis-Steele inclusive scan of transform composition.
  float Ai = A, Bi = Bv;
  for (int off = 1; off < kT; off <<= 1) {
    float pA = 1.0f, pB = 0.0f;
    if (tid >= off) { pA = sA[tid - off]; pB = sB[tid - off]; }
    __syncthreads();
    if (tid >= off) {
      // compose: previous chunk(s) first, then this one
      Bi = Ai * pB + Bi;
      Ai = pA * Ai;
    }
    sA[tid] = Ai; sB[tid] = Bi;
    __syncthreads();
  }
  // y entering chunk t = inclusive B of chunk t-1 (initial state is 0).
  const float y0 = (tid == 0) ? 0.0f : sB[tid - 1];

  // ---------- Pass 2: filtered noise + transient, stash transient in out ---
  float y = y0;
  for (int i = s; i < e; ++i) {
    float x = noise_t[i];
    y = c * x + a * y;                       // filtered[i]
    float t = (float)i * inv;
    float sine = sinf(w * t) * expf(-decay_t * t) * gain_t;
    sine = tanhf(sine * sat);
    float nc = y * expf(-d20 * t) * gh;
    out[i] = sine + nc;                      // transient[i]
  }
  __syncthreads();

  // ---------- Pass 3: resonator ----------
  const float Dd = 48000.0f / freq_r;        // delay in samples (fp32, as ref)
  const int   Bi_band = (int)floorf(Dd);
  const bool  integral = (Dd == floorf(Dd)) && (Bi_band >= 1);

  if (integral) {
    // frac == 0 exactly -> out[i] = tr[i] + (i>=D)*fb*out[i-B].
    // Residue classes mod B are independent chains; value carried in a
    // register, final output fused in.
    for (int cidx = tid; cidx < Bi_band; cidx += kT) {
      float yv = 0.0f;
      for (int i = cidx; i < kN; i += Bi_band) {
        float tr = out[i];
        float dl = (float)i - Dd;
        yv = (dl >= 0.0f) ? (tr + fb * yv) : tr;    // resonator state
        float t = (float)i * inv;
        float env = (1.0f - expf(-att_n * t)) * expf(-dec_n * t);
        float nz = noise_n[i] * env * gain_n;
        out[i] = tr + nz + gain_r * yv;             // final sample
      }
    }
    __syncthreads();
  } else {
    // General fractional delay: banded two-phase update, in place in out[].
    const int Bb = (Bi_band < 1) ? 1 : Bi_band;
    const int nBands = (kN + Bb - 1) / Bb;
    for (int k = 0; k < nBands; ++k) {
      const int start = k * Bb;
      const int end = (start + Bb < kN) ? (start + Bb) : kN;
      // Phase A: first element of the band (it may be read via `ce` by the
      // rest of the band).
      if (tid == 0) {
        int i = start;
        float delayed = (float)i - Dd;
        float validf = (delayed >= 0.0f) ? 1.0f : 0.0f;
        int fl = (int)floorf(delayed);
        fl = fl < 0 ? 0 : (fl > kN - 1 ? kN - 1 : fl);
        int ce = fl + 1 > kN - 1 ? kN - 1 : fl + 1;
        float frac = delayed - (float)fl;            // after clamp, like ref
        float vfl = (fl <= start - 1) ? out[fl] : 0.0f;
        float vce = (ce <= start - 1) ? out[ce] : 0.0f;
        float interp = (1.0f - frac) * vfl + frac * vce;
        out[i] = out[i] + fb * interp * validf;
      }
      __syncthreads();
      // Phase B: rest of the band; all deps are <= start (already final).
      for (int i = start + 1 + tid; i < end; i += kT) {
        float delayed = (float)i - Dd;
        float validf = (delayed >= 0.0f) ? 1.0f : 0.0f;
        int fl = (int)floorf(delayed);
        fl = fl < 0 ? 0 : (fl > kN - 1 ? kN - 1 : fl);
        int ce = fl + 1 > kN - 1 ? kN - 1 : fl + 1;
        float frac = delayed - (float)fl;
        float vfl = (fl <= start) ? out[fl] : 0.0f;
        float vce = (ce <= start) ? out[ce] : 0.0f;
        float interp = (1.0f - frac) * vfl + frac * vce;
        out[i] = out[i] + fb * interp * validf;
      }
      __syncthreads();
    }
    // Final combine (recompute transient: re-walk chunk with saved y0).
    float yy = y0;
    for (int i = s; i < e; ++i) {
      float x = noise_t[i];
      yy = c * x + a * yy;
      float t = (float)i * inv;
      float sine = sinf(w * t) * expf(-decay_t * t) * gain_t;
      sine = tanhf(sine * sat);
      float tr = sine + yy * expf(-d20 * t) * gh;
      float env = (1.0f - expf(-att_n * t)) * expf(-dec_n * t);
      float nz = noise_n[i] * env * gain_n;
      out[i] = tr + nz + gain_r * out[i];
    }
  }
}

extern "C" void kernel_launch(void* const* d_in, const int* in_sizes, int n_in,
                              void* d_out, int out_size, void* d_ws, size_t ws_size,
                              hipStream_t stream) {
  const float* params  = (const float*)d_in[0];
  const float* noise_t = (const float*)d_in[1];
  const float* noise_n = (const float*)d_in[2];
  float* out = (float*)d_out;
  drum_synth_kernel<<<1, kT, 0, stream>>>(params, noise_t, noise_n, out);
}

// Round 2
// 78.898 us; speedup vs baseline: 1.5204x; 1.5204x over previous
//
#include <hip/hip_runtime.h>
#include <math.h>

// ParametricDrumSynth on MI355X — two-kernel latency-parallel rewrite.
//
// K1 (94 blocks x 256): transient[i] -> out[i].
//     one-pole lowpass (c=0.1) truncated to a 200-tap FIR (0.9^200 ~ 7e-10,
//     exact for i<200) => fully parallel, computed as 4 ILP Horner chains.
// K2 (1 block x 512): resonator + noise envelope + final combine.
//     delay = 48000/freq_r = 320.0 exactly (bench) -> frac==0 -> the
//     recurrence is out[i] = tr[i] + fb*out[i-320]: 320 independent chains
//     of 75 steps, register-carried, with a 4-deep manual load prefetch
//     pipeline (loads are independent of the yv dep chain; the compiler
//     cannot reorder them itself across the out[] stores).
//     Non-integral delay: banded two-phase fallback (never taken on bench).

constexpr int   kN    = 24000;
constexpr float kInvT = 1.0f / 23999.0f;   // linspace(0,1,N) step

// ---------------------------------------------------------------- K1 ------
__global__ __launch_bounds__(256) void k1_transient(
    const float* __restrict__ params,
    const float* __restrict__ noise_t,
    float* __restrict__ out)
{
  const int i = blockIdx.x * 256 + threadIdx.x;
  if (i >= kN) return;

  const float decay_t = params[1];
  const float freq_t  = params[2];
  const float sat     = params[3];
  const float gain_t  = params[4];

  // filtered[i] = 0.1 * sum_{k=0}^{199} 0.9^k * x[i-k]
  // split into 4 independent 50-step Horner chains for ILP.
  float p0 = 0.f, p1 = 0.f, p2 = 0.f, p3 = 0.f;
  #pragma unroll
  for (int j = 49; j >= 0; --j) {
    const int b = i - j;
    p0 = fmaf(0.9f, p0, (b        >= 0) ? noise_t[b      ] : 0.0f);
    p1 = fmaf(0.9f, p1, (b -  50  >= 0) ? noise_t[b -  50] : 0.0f);
    p2 = fmaf(0.9f, p2, (b - 100  >= 0) ? noise_t[b - 100] : 0.0f);
    p3 = fmaf(0.9f, p3, (b - 150  >= 0) ? noise_t[b - 150] : 0.0f);
  }
  const float filtered = 0.1f * (p0 + 5.1537752e-3f * p1
                                    + 2.6561399e-5f * p2
                                    + 1.3689148e-7f * p3);

  const float t = (float)i * kInvT;
  float sine = sinf(6.28318530718f * freq_t * t) * expf(-decay_t * t) * gain_t;
  sine = tanhf(sine * sat);
  const float nc = filtered * expf(-decay_t * 20.0f * t) * (gain_t * 0.5f);
  out[i] = sine + nc;                      // transient[i]
}

// ---------------------------------------------------------------- K2 ------
__global__ __launch_bounds__(512) void k2_resonator(
    const float* __restrict__ params,
    const float* __restrict__ noise_t,
    const float* __restrict__ noise_n,
    float* __restrict__ out)
{
  const int tid = threadIdx.x;

  const float decay_t = params[1];
  const float freq_t  = params[2];
  const float sat     = params[3];
  const float gain_t  = params[4];
  const float freq_r  = params[5];
  const float fb      = params[6];
  const float gr      = params[7];
  const float att     = params[8];
  const float dec     = params[9];
  const float gn      = params[10];

  const float Dd = 48000.0f / freq_r;      // delay in samples (fp32, as ref)
  const float fD = floorf(Dd);
  const int   B  = (int)fD;

  if (Dd == fD && B >= 1) {
    // ---------- integral-delay fast path ----------
    for (int c = tid; c < B; c += 512) {
      float yv = 0.0f;

      // guarded pair load
      auto LD = [&](int idx, float& trv, float& nnv) {
        const bool v = idx < kN;
        trv = v ? out[idx]     : 0.0f;
        nnv = v ? noise_n[idx] : 0.0f;
      };
      // one resonator+combine step (no-op past kN)
      auto STEP = [&](int i, float trv, float nnv) {
        if (i < kN) {
          yv = ((float)i - Dd >= 0.0f) ? fmaf(fb, yv, trv) : trv;
          const float t   = (float)i * kInvT;
          const float env = (1.0f - __expf(-att * t)) * __expf(-dec * t);
          out[i] = trv + nnv * env * gn + gr * yv;
        }
      };

      int i0 = c;
      float a0, a1, a2, a3, p0, p1, p2, p3;
      LD(i0,         a0, p0);
      LD(i0 +     B, a1, p1);
      LD(i0 + 2 * B, a2, p2);
      LD(i0 + 3 * B, a3, p3);

      while (i0 < kN) {
        const int i4 = i0 + 4 * B;
        float b0 = 0.f, b1 = 0.f, b2 = 0.f, b3 = 0.f;
        float q0 = 0.f, q1 = 0.f, q2 = 0.f, q3 = 0.f;
        if (i4 < kN) {                 // prefetch next group before computing
          LD(i4,         b0, q0);
          LD(i4 +     B, b1, q1);
          LD(i4 + 2 * B, b2, q2);
          LD(i4 + 3 * B, b3, q3);
        }
        STEP(i0,         a0, p0);
        STEP(i0 +     B, a1, p1);
        STEP(i0 + 2 * B, a2, p2);
        STEP(i0 + 3 * B, a3, p3);
        a0 = b0; a1 = b1; a2 = b2; a3 = b3;
        p0 = q0; p1 = q1; p2 = q2; p3 = q3;
        i0 = i4;
      }
    }
  } else {
    // ---------- general fractional-delay fallback (correctness only) ------
    // out[] holds transient; banded two-phase in-place update reproduces the
    // reference scan's "unwritten entries read as 0" semantics.
    const int Bb = (B < 1) ? 1 : B;
    const int nBands = (kN + Bb - 1) / Bb;
    for (int k = 0; k < nBands; ++k) {
      const int start = k * Bb;
      const int end = (start + Bb < kN) ? (start + Bb) : kN;
      if (tid == 0) {
        const int i = start;
        const float delayed = (float)i - Dd;
        const float validf = (delayed >= 0.0f) ? 1.0f : 0.0f;
        int fl = (int)floorf(delayed);
        fl = fl < 0 ? 0 : (fl > kN - 1 ? kN - 1 : fl);
        const int ce = fl + 1 > kN - 1 ? kN - 1 : fl + 1;
        const float frac = delayed - (float)fl;
        const float vfl = (fl <= start - 1) ? out[fl] : 0.0f;
        const float vce = (ce <= start - 1) ? out[ce] : 0.0f;
        out[i] = out[i] + fb * ((1.0f - frac) * vfl + frac * vce) * validf;
      }
      __syncthreads();
      for (int i = start + 1 + tid; i < end; i += 512) {
        const float delayed = (float)i - Dd;
        const float validf = (delayed >= 0.0f) ? 1.0f : 0.0f;
        int fl = (int)floorf(delayed);
        fl = fl < 0 ? 0 : (fl > kN - 1 ? kN - 1 : fl);
        const int ce = fl + 1 > kN - 1 ? kN - 1 : fl + 1;
        const float frac = delayed - (float)fl;
        const float vfl = (fl <= start) ? out[fl] : 0.0f;
        const float vce = (ce <= start) ? out[ce] : 0.0f;
        out[i] = out[i] + fb * ((1.0f - frac) * vfl + frac * vce) * validf;
      }
      __syncthreads();
    }
    // final combine: out = transient + noise + gain_r * res
    // (transient recomputed from scratch; fallback path, perf irrelevant)
    for (int i = tid; i < kN; i += 512) {
      float p0 = 0.f, p1 = 0.f, p2 = 0.f, p3 = 0.f;
      for (int j = 49; j >= 0; --j) {
        const int b = i - j;
        p0 = fmaf(0.9f, p0, (b        >= 0) ? noise_t[b      ] : 0.0f);
        p1 = fmaf(0.9f, p1, (b -  50  >= 0) ? noise_t[b -  50] : 0.0f);
        p2 = fmaf(0.9f, p2, (b - 100  >= 0) ? noise_t[b - 100] : 0.0f);
        p3 = fmaf(0.9f, p3, (b - 150  >= 0) ? noise_t[b - 150] : 0.0f);
      }
      const float filtered = 0.1f * (p0 + 5.1537752e-3f * p1
                                        + 2.6561399e-5f * p2
                                        + 1.3689148e-7f * p3);
      const float t = (float)i * kInvT;
      float sine = sinf(6.28318530718f * freq_t * t) * expf(-decay_t * t) * gain_t;
      sine = tanhf(sine * sat);
      const float tr = sine + filtered * expf(-decay_t * 20.0f * t) * (gain_t * 0.5f);
      const float env = (1.0f - expf(-att * t)) * expf(-dec * t);
      out[i] = tr + noise_n[i] * env * gn + gr * out[i];
    }
  }
}

extern "C" void kernel_launch(void* const* d_in, const int* in_sizes, int n_in,
                              void* d_out, int out_size, void* d_ws, size_t ws_size,
                              hipStream_t stream) {
  const float* params  = (const float*)d_in[0];
  const float* noise_t = (const float*)d_in[1];
  const float* noise_n = (const float*)d_in[2];
  float* out = (float*)d_out;

  k1_transient<<<(kN + 255) / 256, 256, 0, stream>>>(params, noise_t, out);
  k2_resonator<<<1, 512, 0, stream>>>(params, noise_t, noise_n, out);
}

// Round 3
// 69.184 us; speedup vs baseline: 1.7339x; 1.1404x over previous
//
#include <hip/hip_runtime.h>
#include <math.h>

// ParametricDrumSynth on MI355X — fully parallel two-kernel form.
//
// K1 (94x256): transient -> ws_tr.  One-pole lowpass truncated to 64-tap FIR
//     (0.9^64 ~ 1.2e-3; error << 5.2e-2 threshold), 4x16 ILP Horner chains,
//     fast transcendentals.
// K2 (94x256): resonator in CLOSED FORM.  delay = 48000/freq_r = 320.0 is
//     integral (bench) -> frac == 0 -> recurrence expands to
//        res[i] = sum_{m=0..i/B} fb^m * tr[i - m*B]
//     i.e. a <=75-tap strided convolution: embarrassingly parallel, lane-
//     coalesced loads, 3-way Horner split (ratio fb^3) for ILP.  tr lives in
//     d_ws so there is no read/write race on d_out.
//     Non-integral delay: banded serial fallback in block 0 (never taken on
//     the bench parameters; correctness only).

constexpr int   kN    = 24000;
constexpr float kInvT = 1.0f / 23999.0f;   // linspace(0,1,N) step

// ---------------------------------------------------------------- K1 ------
__global__ __launch_bounds__(256) void k1_transient(
    const float* __restrict__ params,
    const float* __restrict__ noise_t,
    float* __restrict__ tr)
{
  const int i = blockIdx.x * 256 + threadIdx.x;
  if (i >= kN) return;

  const float decay_t = params[1];
  const float freq_t  = params[2];
  const float sat     = params[3];
  const float gain_t  = params[4];

  // filtered[i] = 0.1 * sum_{k=0}^{63} 0.9^k x[i-k], 4x16 Horner chains.
  float p0 = 0.f, p1 = 0.f, p2 = 0.f, p3 = 0.f;
  #pragma unroll
  for (int j = 15; j >= 0; --j) {
    const int b = i - j;
    p0 = fmaf(0.9f, p0, (b      >= 0) ? noise_t[b     ] : 0.0f);
    p1 = fmaf(0.9f, p1, (b - 16 >= 0) ? noise_t[b - 16] : 0.0f);
    p2 = fmaf(0.9f, p2, (b - 32 >= 0) ? noise_t[b - 32] : 0.0f);
    p3 = fmaf(0.9f, p3, (b - 48 >= 0) ? noise_t[b - 48] : 0.0f);
  }
  const float filtered = 0.1f * (p0 + 0.185302019f * p1
                                    + 0.034336838f * p2
                                    + 0.006362685f * p3);

  const float t = (float)i * kInvT;
  float s = __sinf(6.28318530718f * freq_t * t) * __expf(-decay_t * t) * gain_t;
  // tanh(sat*s) = 1 - 2/(exp(2*sat*s)+1)
  const float e2 = __expf(2.0f * sat * s);
  s = 1.0f - 2.0f / (e2 + 1.0f);
  const float nc = filtered * __expf(-decay_t * 20.0f * t) * (gain_t * 0.5f);
  tr[i] = s + nc;
}

// ---------------------------------------------------------------- K2 ------
__global__ __launch_bounds__(256) void k2_combine(
    const float* __restrict__ params,
    const float* __restrict__ noise_n,
    const float* __restrict__ tr,     // ws_tr (from K1)
    float* __restrict__ res_ws,       // scratch for fallback path only
    float* __restrict__ out)
{
  const float fb  = params[6];
  const float gr  = params[7];
  const float att = params[8];
  const float dec = params[9];
  const float gn  = params[10];

  const float Dd = 48000.0f / params[5];   // delay in samples (fp32, as ref)
  const float fD = floorf(Dd);
  const int   B  = (int)fD;

  if (Dd == fD && B >= 1) {
    // -------- integral delay: closed-form convolution, fully parallel -----
    const int i = blockIdx.x * 256 + threadIdx.x;
    if (i >= kN) return;

    const int   Mmax = (kN - 1) / B;       // wave-uniform (74 on bench)
    const int   J    = Mmax / 3 + 1;       // taps per chain (25)
    const float fb3  = fb * fb * fb;

    float p0 = 0.f, p1 = 0.f, p2 = 0.f;
    for (int j = J - 1; j >= 0; --j) {     // high m first: invalid taps add 0
      const int i0 = i - 3 * j * B;        // tap m = 3j
      const int i1 = i0 - B;               // tap m = 3j+1
      const int i2 = i1 - B;               // tap m = 3j+2
      p0 = fmaf(fb3, p0, (i0 >= 0) ? tr[i0] : 0.0f);
      p1 = fmaf(fb3, p1, (i1 >= 0) ? tr[i1] : 0.0f);
      p2 = fmaf(fb3, p2, (i2 >= 0) ? tr[i2] : 0.0f);
    }
    const float res = p0 + fb * p1 + (fb * fb) * p2;   // includes m=0 (=tr[i])

    const float t   = (float)i * kInvT;
    const float env = (1.0f - __expf(-att * t)) * __expf(-dec * t);
    out[i] = tr[i] + noise_n[i] * env * gn + gr * res;
  } else {
    // -------- general fractional delay: serial banded fallback (block 0) --
    if (blockIdx.x != 0) return;
    const int tid = threadIdx.x;
    const int Bb = (B < 1) ? 1 : B;
    const int nBands = (kN + Bb - 1) / Bb;
    // res_ws[i] = tr[i] + fb*interp(res_ws)*valid, scan order; unwritten
    // entries read as 0 (reference scan semantics), so no zero-init needed.
    for (int k = 0; k < nBands; ++k) {
      const int start = k * Bb;
      const int end = (start + Bb < kN) ? (start + Bb) : kN;
      if (tid == 0) {
        const int i = start;
        const float delayed = (float)i - Dd;
        const float validf = (delayed >= 0.0f) ? 1.0f : 0.0f;
        int fl = (int)floorf(delayed);
        fl = fl < 0 ? 0 : (fl > kN - 1 ? kN - 1 : fl);
        const int ce = fl + 1 > kN - 1 ? kN - 1 : fl + 1;
        const float frac = delayed - (float)fl;
        const float vfl = (fl <= start - 1) ? res_ws[fl] : 0.0f;
        const float vce = (ce <= start - 1) ? res_ws[ce] : 0.0f;
        res_ws[i] = tr[i] + fb * ((1.0f - frac) * vfl + frac * vce) * validf;
      }
      __syncthreads();
      for (int i = start + 1 + tid; i < end; i += 256) {
        const float delayed = (float)i - Dd;
        const float validf = (delayed >= 0.0f) ? 1.0f : 0.0f;
        int fl = (int)floorf(delayed);
        fl = fl < 0 ? 0 : (fl > kN - 1 ? kN - 1 : fl);
        const int ce = fl + 1 > kN - 1 ? kN - 1 : fl + 1;
        const float frac = delayed - (float)fl;
        const float vfl = (fl <= start) ? res_ws[fl] : 0.0f;
        const float vce = (ce <= start) ? res_ws[ce] : 0.0f;
        res_ws[i] = tr[i] + fb * ((1.0f - frac) * vfl + frac * vce) * validf;
      }
      __syncthreads();
    }
    for (int i = tid; i < kN; i += 256) {
      const float t   = (float)i * kInvT;
      const float env = (1.0f - __expf(-att * t)) * __expf(-dec * t);
      out[i] = tr[i] + noise_n[i] * env * gn + gr * res_ws[i];
    }
  }
}

extern "C" void kernel_launch(void* const* d_in, const int* in_sizes, int n_in,
                              void* d_out, int out_size, void* d_ws, size_t ws_size,
                              hipStream_t stream) {
  const float* params  = (const float*)d_in[0];
  const float* noise_t = (const float*)d_in[1];
  const float* noise_n = (const float*)d_in[2];
  float* out = (float*)d_out;
  float* ws_tr  = (float*)d_ws;            // 24000 floats
  float* ws_res = (float*)d_ws + kN;       // 24000 floats (fallback only)

  const int nb = (kN + 255) / 256;         // 94 blocks
  k1_transient<<<nb, 256, 0, stream>>>(params, noise_t, ws_tr);
  k2_combine<<<nb, 256, 0, stream>>>(params, noise_n, ws_tr, ws_res, out);
}

// Round 4
// 63.153 us; speedup vs baseline: 1.8995x; 1.0955x over previous
//
#include <hip/hip_runtime.h>
#include <math.h>

// ParametricDrumSynth on MI355X — fully parallel two-kernel form, R4.
//
// K1 (375x64): transient -> ws_tr.  One-pole lowpass truncated to 64-tap FIR
//     (0.9^64 ~ 1.2e-3; error << 5.2e-2 threshold), 4x16 ILP Horner chains,
//     fast transcendentals.  Unguarded loads for i >= 63.
// K2 (375x64): resonator in CLOSED FORM.  delay = 48000/freq_r integral
//     (bench: 320.0) -> frac == 0 -> recurrence expands to
//        res[i] = sum_{m=0..i/B} fb^m * tr[i - m*B]   (<= 75 taps)
//     Fully-unrolled JMAX=25 x 3-chain Horner whenever B >= 320 (compile-time
//     trip count: compiler hoists all 75 independent loads -> one latency
//     exposure instead of 25 serialized L2 round-trips).  Taps with i0 < 0
//     contribute exact zeros through the chain, so the unrolled form is valid
//     for ALL B >= 320, not just 320.  Runtime loop for 1 <= B < 320;
//     serial banded fallback for non-integral delay (never taken on bench).

constexpr int   kN    = 24000;
constexpr float kInvT = 1.0f / 23999.0f;   // linspace(0,1,N) step
constexpr int   kBT   = 64;                // block size (1 wave)

// ---------------------------------------------------------------- K1 ------
__global__ __launch_bounds__(kBT) void k1_transient(
    const float* __restrict__ params,
    const float* __restrict__ noise_t,
    float* __restrict__ tr)
{
  const int i = blockIdx.x * kBT + threadIdx.x;
  if (i >= kN) return;

  const float decay_t = params[1];
  const float freq_t  = params[2];
  const float sat     = params[3];
  const float gain_t  = params[4];

  // filtered[i] = 0.1 * sum_{k=0}^{63} 0.9^k x[i-k], 4x16 Horner chains.
  float p0 = 0.f, p1 = 0.f, p2 = 0.f, p3 = 0.f;
  if (i >= 63) {                           // fast path: no guards
    #pragma unroll
    for (int j = 15; j >= 0; --j) {
      const int b = i - j;
      p0 = fmaf(0.9f, p0, noise_t[b     ]);
      p1 = fmaf(0.9f, p1, noise_t[b - 16]);
      p2 = fmaf(0.9f, p2, noise_t[b - 32]);
      p3 = fmaf(0.9f, p3, noise_t[b - 48]);
    }
  } else {
    #pragma unroll
    for (int j = 15; j >= 0; --j) {
      const int b = i - j;
      p0 = fmaf(0.9f, p0, (b      >= 0) ? noise_t[b     ] : 0.0f);
      p1 = fmaf(0.9f, p1, (b - 16 >= 0) ? noise_t[b - 16] : 0.0f);
      p2 = fmaf(0.9f, p2, (b - 32 >= 0) ? noise_t[b - 32] : 0.0f);
      p3 = fmaf(0.9f, p3, (b - 48 >= 0) ? noise_t[b - 48] : 0.0f);
    }
  }
  const float filtered = 0.1f * (p0 + 0.185302019f * p1
                                    + 0.034336838f * p2
                                    + 0.006362685f * p3);

  const float t = (float)i * kInvT;
  float s = __sinf(6.28318530718f * freq_t * t) * __expf(-decay_t * t) * gain_t;
  // tanh(sat*s) = 1 - 2/(exp(2*sat*s)+1)
  const float e2 = __expf(2.0f * sat * s);
  s = 1.0f - 2.0f / (e2 + 1.0f);
  const float nc = filtered * __expf(-decay_t * 20.0f * t) * (gain_t * 0.5f);
  tr[i] = s + nc;
}

// ---------------------------------------------------------------- K2 ------
__global__ __launch_bounds__(kBT) void k2_combine(
    const float* __restrict__ params,
    const float* __restrict__ noise_n,
    const float* __restrict__ tr,     // ws_tr (from K1)
    float* __restrict__ res_ws,       // scratch for fallback path only
    float* __restrict__ out)
{
  const float fb  = params[6];
  const float gr  = params[7];
  const float att = params[8];
  const float dec = params[9];
  const float gn  = params[10];

  const float Dd = 48000.0f / params[5];   // delay in samples (fp32, as ref)
  const float fD = floorf(Dd);
  const int   B  = (int)fD;

  if (Dd == fD && B >= 1) {
    // -------- integral delay: closed-form convolution, fully parallel -----
    const int i = blockIdx.x * kBT + threadIdx.x;
    if (i >= kN) return;

    const float fb3 = fb * fb * fb;
    float res;

    if (B >= 320) {
      // Mmax <= 74 -> JMAX = 25 covers every tap; compile-time unroll.
      float p0 = 0.f, p1 = 0.f, p2 = 0.f;
      #pragma unroll
      for (int j = 24; j >= 0; --j) {      // high m first: invalid taps add 0
        const int i0 = i - 3 * j * B;      // tap m = 3j
        const int i1 = i0 - B;             // tap m = 3j+1
        const int i2 = i1 - B;             // tap m = 3j+2
        p0 = fmaf(fb3, p0, (i0 >= 0) ? tr[i0] : 0.0f);
        p1 = fmaf(fb3, p1, (i1 >= 0) ? tr[i1] : 0.0f);
        p2 = fmaf(fb3, p2, (i2 >= 0) ? tr[i2] : 0.0f);
      }
      res = p0 + fb * p1 + (fb * fb) * p2; // includes m=0 (= tr[i])
    } else {
      // small-delay integral case (not the bench): runtime trip count.
      const int Mmax = (kN - 1) / B;
      const int J    = Mmax / 3 + 1;
      float p0 = 0.f, p1 = 0.f, p2 = 0.f;
      for (int j = J - 1; j >= 0; --j) {
        const int i0 = i - 3 * j * B;
        const int i1 = i0 - B;
        const int i2 = i1 - B;
        p0 = fmaf(fb3, p0, (i0 >= 0) ? tr[i0] : 0.0f);
        p1 = fmaf(fb3, p1, (i1 >= 0) ? tr[i1] : 0.0f);
        p2 = fmaf(fb3, p2, (i2 >= 0) ? tr[i2] : 0.0f);
      }
      res = p0 + fb * p1 + (fb * fb) * p2;
    }

    const float t   = (float)i * kInvT;
    const float env = (1.0f - __expf(-att * t)) * __expf(-dec * t);
    out[i] = tr[i] + noise_n[i] * env * gn + gr * res;
  } else {
    // -------- general fractional delay: serial banded fallback (block 0) --
    if (blockIdx.x != 0) return;
    const int tid = threadIdx.x;
    const int Bb = (B < 1) ? 1 : B;
    const int nBands = (kN + Bb - 1) / Bb;
    // res_ws[i] = tr[i] + fb*interp(res_ws)*valid, scan order; unwritten
    // entries read as 0 (reference scan semantics), so no zero-init needed.
    for (int k = 0; k < nBands; ++k) {
      const int start = k * Bb;
      const int end = (start + Bb < kN) ? (start + Bb) : kN;
      if (tid == 0) {
        const int i = start;
        const float delayed = (float)i - Dd;
        const float validf = (delayed >= 0.0f) ? 1.0f : 0.0f;
        int fl = (int)floorf(delayed);
        fl = fl < 0 ? 0 : (fl > kN - 1 ? kN - 1 : fl);
        const int ce = fl + 1 > kN - 1 ? kN - 1 : fl + 1;
        const float frac = delayed - (float)fl;
        const float vfl = (fl <= start - 1) ? res_ws[fl] : 0.0f;
        const float vce = (ce <= start - 1) ? res_ws[ce] : 0.0f;
        res_ws[i] = tr[i] + fb * ((1.0f - frac) * vfl + frac * vce) * validf;
      }
      __syncthreads();
      for (int i = start + 1 + tid; i < end; i += kBT) {
        const float delayed = (float)i - Dd;
        const float validf = (delayed >= 0.0f) ? 1.0f : 0.0f;
        int fl = (int)floorf(delayed);
        fl = fl < 0 ? 0 : (fl > kN - 1 ? kN - 1 : fl);
        const int ce = fl + 1 > kN - 1 ? kN - 1 : fl + 1;
        const float frac = delayed - (float)fl;
        const float vfl = (fl <= start) ? res_ws[fl] : 0.0f;
        const float vce = (ce <= start) ? res_ws[ce] : 0.0f;
        res_ws[i] = tr[i] + fb * ((1.0f - frac) * vfl + frac * vce) * validf;
      }
      __syncthreads();
    }
    for (int i = tid; i < kN; i += kBT) {
      const float t   = (float)i * kInvT;
      const float env = (1.0f - __expf(-att * t)) * __expf(-dec * t);
      out[i] = tr[i] + noise_n[i] * env * gn + gr * res_ws[i];
    }
  }
}

extern "C" void kernel_launch(void* const* d_in, const int* in_sizes, int n_in,
                              void* d_out, int out_size, void* d_ws, size_t ws_size,
                              hipStream_t stream) {
  const float* params  = (const float*)d_in[0];
  const float* noise_t = (const float*)d_in[1];
  const float* noise_n = (const float*)d_in[2];
  float* out = (float*)d_out;
  float* ws_tr  = (float*)d_ws;            // 24000 floats
  float* ws_res = (float*)d_ws + kN;       // 24000 floats (fallback only)

  const int nb = (kN + kBT - 1) / kBT;     // 375 blocks -> all 256 CUs touched
  k1_transient<<<nb, kBT, 0, stream>>>(params, noise_t, ws_tr);
  k2_combine<<<nb, kBT, 0, stream>>>(params, noise_n, ws_tr, ws_res, out);
}